// Round 5
// baseline (140.600 us; speedup 1.0000x reference)
//
#include <hip/hip_runtime.h>
#include <hip/hip_bf16.h>

#define SEQ 2048
#define EMB 1024
#define NH 8
#define HD 64
#define DVH 128
#define LAMBDA_INIT 0.7836057665316245f
#define ONE_MINUS_LI 0.2163942334683755f
#define RMS_EPS 1e-5f

typedef __attribute__((ext_vector_type(8))) short short8_t;
typedef __attribute__((ext_vector_type(4))) float f32x4;

__device__ __forceinline__ short f2bf(float f) {
    __hip_bfloat16 h = __float2bfloat16(f);
    return *reinterpret_cast<short*>(&h);
}
__device__ __forceinline__ float bf2f(short s) {
    unsigned u = ((unsigned)(unsigned short)s) << 16;
    return __uint_as_float(u);
}
__device__ __forceinline__ void gload16(const void* g, void* l) {
    __builtin_amdgcn_global_load_lds((const __attribute__((address_space(1))) unsigned int*)g,
                                     (__attribute__((address_space(3))) unsigned int*)l, 16, 0, 0);
}

// ---------- prep: x f32 -> bf16 ----------
__global__ void k_convert_x(const float* __restrict__ x, short* __restrict__ xb) {
    int i = blockIdx.x * blockDim.x + threadIdx.x;
    const float4* xv = (const float4*)x;
    float4 v = xv[i];
    short4 r = make_short4(f2bf(v.x), f2bf(v.y), f2bf(v.z), f2bf(v.w));
    *(short4*)(xb + i * 4) = r;
}

// ---------- prep: weights f32 (K,N) -> bf16 transposed (N,K) ----------
__global__ void k_transpose_w(const float* __restrict__ w0, const float* __restrict__ w1,
                              const float* __restrict__ w2, const float* __restrict__ w3,
                              short* __restrict__ o0, short* __restrict__ o1,
                              short* __restrict__ o2, short* __restrict__ o3) {
    const float* w = blockIdx.z == 0 ? w0 : blockIdx.z == 1 ? w1 : blockIdx.z == 2 ? w2 : w3;
    short* o = blockIdx.z == 0 ? o0 : blockIdx.z == 1 ? o1 : blockIdx.z == 2 ? o2 : o3;
    __shared__ float t[64][65];
    int r0 = blockIdx.y * 64, c0 = blockIdx.x * 64;
    int tid = threadIdx.x, col = tid & 63, rb = tid >> 6;
#pragma unroll
    for (int i = 0; i < 16; i++) {
        int row = rb + i * 4;
        t[row][col] = w[(r0 + row) * EMB + c0 + col];
    }
    __syncthreads();
#pragma unroll
    for (int i = 0; i < 16; i++) {
        int fr = rb + i * 4;
        o[(c0 + fr) * EMB + r0 + col] = f2bf(t[col][fr]);
    }
}

// ---------- prep: lambda scalar ----------
__global__ void k_lambda(const float* __restrict__ lq1, const float* __restrict__ lk1,
                         const float* __restrict__ lq2, const float* __restrict__ lk2,
                         float* __restrict__ lam) {
    int l = threadIdx.x;
    float p1 = lq1[l] * lk1[l], p2 = lq2[l] * lk2[l];
#pragma unroll
    for (int off = 32; off >= 1; off >>= 1) {
        p1 += __shfl_xor(p1, off);
        p2 += __shfl_xor(p2, off);
    }
    if (l == 0) lam[0] = expf(p1) - expf(p2) + LAMBDA_INIT;
}

// ---------- m97-style tiled GEMM: C = A(M,K) * Bt(N,K)^T ----------
template <int MI, int NI, int OUTM>
__global__ __launch_bounds__(256) void k_gemm(const short* __restrict__ A,
                                              const short* __restrict__ B0,
                                              const short* __restrict__ B1,
                                              const short* __restrict__ B2,
                                              short* __restrict__ Cq, short* __restrict__ Ck,
                                              short* __restrict__ Cv, float* __restrict__ Cf) {
    constexpr int BM = MI * 32, BN = NI * 32, BK = 64;
    __shared__ short Abuf[BM * BK];
    __shared__ short Bbuf[BN * BK];
    const int bn = blockIdx.x * BN;
    const int bm = blockIdx.y * BM;
    const int nsel = bn >> 10;
    const int nloc = bn & 1023;
    const short* Bt = nsel == 0 ? B0 : (nsel == 1 ? B1 : B2);
    const int tid = threadIdx.x;
    const int w = tid >> 6, l = tid & 63;
    const int lr = l & 15, lg = l >> 4;
    const int wm = (w >> 1) * (MI * 16), wn = (w & 1) * (NI * 16);
    const int lrow8 = l >> 3, lchunk = l & 7;
    const int schunk = (lchunk ^ lrow8) * 8;

    f32x4 acc[MI][NI];
#pragma unroll
    for (int mi = 0; mi < MI; mi++)
#pragma unroll
        for (int ni = 0; ni < NI; ni++) acc[mi][ni] = f32x4{0.f, 0.f, 0.f, 0.f};

    for (int k0 = 0; k0 < EMB; k0 += BK) {
#pragma unroll
        for (int j = 0; j < BM / 32; j++) {
            int r0 = w * (BM / 4) + j * 8;
            gload16(A + (size_t)(bm + r0 + lrow8) * EMB + k0 + schunk, &Abuf[r0 * BK]);
        }
#pragma unroll
        for (int j = 0; j < BN / 32; j++) {
            int r0 = w * (BN / 4) + j * 8;
            gload16(Bt + (size_t)(nloc + r0 + lrow8) * EMB + k0 + schunk, &Bbuf[r0 * BK]);
        }
        __syncthreads();
#pragma unroll
        for (int kk = 0; kk < 2; kk++) {
            const int pcs = (((kk << 2) + lg) ^ (lr & 7)) << 3;
            short8_t af[MI], bf[NI];
#pragma unroll
            for (int mi = 0; mi < MI; mi++)
                af[mi] = *(const short8_t*)&Abuf[(wm + mi * 16 + lr) * BK + pcs];
#pragma unroll
            for (int ni = 0; ni < NI; ni++)
                bf[ni] = *(const short8_t*)&Bbuf[(wn + ni * 16 + lr) * BK + pcs];
#pragma unroll
            for (int mi = 0; mi < MI; mi++)
#pragma unroll
                for (int ni = 0; ni < NI; ni++)
                    acc[mi][ni] =
                        __builtin_amdgcn_mfma_f32_16x16x32_bf16(af[mi], bf[ni], acc[mi][ni], 0, 0, 0);
        }
        __syncthreads();
    }
#pragma unroll
    for (int mi = 0; mi < MI; mi++)
#pragma unroll
        for (int ni = 0; ni < NI; ni++)
#pragma unroll
            for (int r = 0; r < 4; r++) {
                int row = bm + wm + mi * 16 + lg * 4 + r;
                int col = wn + ni * 16 + lr;
                if (OUTM == 0) {
                    if (nsel < 2) {
                        int ci = nloc + col;
                        int hh = ci >> 7, c = ci & 127;
                        (nsel == 0 ? Cq : Ck)[(hh << 18) + row * 128 + c] = f2bf(acc[mi][ni][r]);
                    } else {
                        Cv[row * EMB + nloc + col] = f2bf(acc[mi][ni][r]);
                    }
                } else {
                    Cf[row * EMB + bn + col] = acc[mi][ni][r];
                }
            }
}

// ---------- RoPE on Qh,Kh in place ----------
__global__ void k_rope(short* __restrict__ Qh, short* __restrict__ Kh,
                       const float* __restrict__ cosT, const float* __restrict__ sinT) {
    int i = blockIdx.x * blockDim.x + threadIdx.x;
    int s = (i >> 6) & 2047;
    int jf = i & 31;
    float c = cosT[s * 32 + jf], sn = sinT[s * 32 + jf];
    unsigned* qw = reinterpret_cast<unsigned*>(Qh);
    unsigned* kw = reinterpret_cast<unsigned*>(Kh);
    unsigned v = qw[i];
    float e = bf2f((short)(v & 0xffff)), o = bf2f((short)(v >> 16));
    float r1 = e * c - o * sn, r2 = e * sn + o * c;
    qw[i] = ((unsigned)(unsigned short)f2bf(r2) << 16) | (unsigned)(unsigned short)f2bf(r1);
    v = kw[i];
    e = bf2f((short)(v & 0xffff));
    o = bf2f((short)(v >> 16));
    r1 = e * c - o * sn;
    r2 = e * sn + o * c;
    kw[i] = ((unsigned)(unsigned short)f2bf(r2) << 16) | (unsigned)(unsigned short)f2bf(r1);
}

// ---------- V transpose: (S, EMB) -> (EMB, S) ----------
__global__ void k_transpose_v(const short* __restrict__ Vb, short* __restrict__ Vt) {
    __shared__ short t[64][65];
    int s0 = blockIdx.x * 64, f0 = blockIdx.y * 64;
    int tid = threadIdx.x, col = tid & 63, rb = tid >> 6;
#pragma unroll
    for (int i = 0; i < 16; i++) {
        int row = rb + i * 4;
        t[row][col] = Vb[(s0 + row) * EMB + f0 + col];
    }
    __syncthreads();
#pragma unroll
    for (int i = 0; i < 16; i++) {
        int fr = rb + i * 4;
        Vt[(f0 + fr) * SEQ + s0 + col] = t[col][fr];
    }
}

// ---------- fused differential flash attention, LDS-staged KV pipeline ----------
// Block: 2 q-tiles (bx, 127-bx) x 2 lambda-components = 4 waves, each owning
// one (tile,comp) 16-row chain. K (32x128) + V^T (128x32) staged to LDS per KV
// step via global_load_lds w=16, double-buffered, counted vmcnt(4) + raw
// s_barrier (loads stay in flight across barriers). XOR chunk swizzles applied
// on global source + matched on LDS reads (both-sides rule).
__global__ __launch_bounds__(256) void k_attn(const short* __restrict__ Qh,
                                              const short* __restrict__ Kh,
                                              const short* __restrict__ Vt,
                                              const float* __restrict__ lamp,
                                              const float* __restrict__ subln,
                                              short* __restrict__ Ab) {
    const int h = blockIdx.y;
    const int bx = blockIdx.x;
    const int q0a = bx * 16;
    const int q0b = (127 - bx) * 16;
    const int tid = threadIdx.x;
    const int w = tid >> 6, l = tid & 63;
    const int lq = l & 15, lg = l >> 4;
    const int tile = w >> 1, comp = w & 1;
    const int q0 = tile ? q0b : q0a;
    const float lam = lamp[0];

    __shared__ __align__(16) short KB[2][32][128];
    __shared__ __align__(16) short VB[2][128][32];
    __shared__ __align__(16) short PL[4][16][40];
    __shared__ __align__(16) float OC[4][16][128];
    __shared__ float MLs[4][16];

    const short* kbase = Kh + ((size_t)h << 18);
    const short* vtb = Vt + ((size_t)h * 128) * SEQ;

    const int nt = ((q0b + 16) + 31) >> 5;            // uniform loop count (b is longer)
    const int myNt = tile ? nt : (((q0a + 16) + 31) >> 5);

    // Q fragments for my (tile, comp)
    short8_t qf[2];
    {
        const short* qp = Qh + ((size_t)h << 18) + (size_t)(q0 + lq) * 128 + (comp << 6) + lg * 8;
        qf[0] = *(const short8_t*)(qp);
        qf[1] = *(const short8_t*)(qp + 32);
    }
    f32x4 zero4 = {0.f, 0.f, 0.f, 0.f};
    f32x4 o[8];
#pragma unroll
    for (int dt = 0; dt < 8; dt++) o[dt] = zero4;
    float m = -1e30f, lsum = 0.f;

    short* myP = &PL[w][0][0];
    unsigned* myP32 = reinterpret_cast<unsigned*>(myP);

    // staging lane constants
    const int kr0 = w * 8 + (l >> 4);   // K row for j=0 (j=1: +4)
    const int kc = l & 15;              // K chunk (16B)
    const int vr0 = w * 32 + (l >> 2);  // V row for j=0 (j=1: +16)
    const int vc = l & 3;               // V chunk

#define STAGE(BUF, KT)                                                                       \
    {                                                                                        \
        const int k0s = (KT) * 32;                                                           \
        {                                                                                    \
            int kr = kr0;                                                                    \
            gload16(kbase + (size_t)(k0s + kr) * 128 + ((kc ^ (kr & 7)) << 3),               \
                    &KB[BUF][w * 8][0]);                                                     \
            kr = kr0 + 4;                                                                    \
            gload16(kbase + (size_t)(k0s + kr) * 128 + ((kc ^ (kr & 7)) << 3),               \
                    &KB[BUF][w * 8 + 4][0]);                                                 \
        }                                                                                    \
        {                                                                                    \
            int vr = vr0;                                                                    \
            gload16(vtb + (size_t)vr * SEQ + k0s + ((vc ^ (vr & 3)) << 3),                   \
                    &VB[BUF][w * 32][0]);                                                    \
            vr = vr0 + 16;                                                                   \
            gload16(vtb + (size_t)vr * SEQ + k0s + ((vc ^ (vr & 3)) << 3),                   \
                    &VB[BUF][w * 32 + 16][0]);                                               \
        }                                                                                    \
    }

    STAGE(0, 0);
    for (int t = 0; t < nt; ++t) {
        const int cur = t & 1;
        if (t + 1 < nt) {
            STAGE(cur ^ 1, t + 1);
            asm volatile("s_waitcnt vmcnt(4)" ::: "memory");
        } else {
            asm volatile("s_waitcnt vmcnt(0)" ::: "memory");
        }
        __builtin_amdgcn_s_barrier();
        __builtin_amdgcn_sched_barrier(0);
        if (t < myNt) {
            const int k0 = t * 32;
            // K fragments from LDS (swizzled)
            short8_t kf[2][2];
#pragma unroll
            for (int tt = 0; tt < 2; tt++)
#pragma unroll
                for (int s = 0; s < 2; s++)
                    kf[tt][s] = *(const short8_t*)&KB[cur][16 * tt + lq]
                                                      [(((comp << 3) + (s << 2) + lg) ^ (lq & 7)) << 3];
            // V fragments from LDS (swizzled)
            short8_t vf[8];
#pragma unroll
            for (int dt = 0; dt < 8; dt++)
                vf[dt] = *(const short8_t*)&VB[cur][dt * 16 + lq][(lg ^ (lq & 3)) << 3];
            // S^T = K * Q
            f32x4 s[2];
#pragma unroll
            for (int tt = 0; tt < 2; tt++) {
                s[tt] = zero4;
                s[tt] = __builtin_amdgcn_mfma_f32_16x16x32_bf16(kf[tt][0], qf[0], s[tt], 0, 0, 0);
                s[tt] = __builtin_amdgcn_mfma_f32_16x16x32_bf16(kf[tt][1], qf[1], s[tt], 0, 0, 0);
            }
            // softmax (swapped layout, deferred rescale) + P bounce + PV
            float sv[8];
#pragma unroll
            for (int tt = 0; tt < 2; tt++)
#pragma unroll
                for (int r = 0; r < 4; r++) sv[tt * 4 + r] = s[tt][r] * 0.125f;
            if (k0 + 31 > q0) {
#pragma unroll
                for (int tt = 0; tt < 2; tt++)
#pragma unroll
                    for (int r = 0; r < 4; r++)
                        if (k0 + tt * 16 + lg * 4 + r > q0 + lq) sv[tt * 4 + r] = -1e30f;
            }
            float t1 = sv[0];
#pragma unroll
            for (int i = 1; i < 8; i++) t1 = fmaxf(t1, sv[i]);
            t1 = fmaxf(t1, __shfl_xor(t1, 16));
            t1 = fmaxf(t1, __shfl_xor(t1, 32));
            if (!__all(t1 <= m + 8.f)) {
                float mn = fmaxf(m, t1);
                float al = __expf(m - mn);
                m = mn;
                lsum *= al;
                float ar[4];
#pragma unroll
                for (int r = 0; r < 4; r++) ar[r] = __shfl(al, lg * 4 + r);
#pragma unroll
                for (int dt = 0; dt < 8; dt++)
#pragma unroll
                    for (int r = 0; r < 4; r++) o[dt][r] *= ar[r];
            }
            float p[8];
#pragma unroll
            for (int i = 0; i < 8; i++) {
                p[i] = __expf(sv[i] - m);
                lsum += p[i];
            }
#pragma unroll
            for (int tt = 0; tt < 2; tt++) {
                unsigned u0 = ((unsigned)(unsigned short)f2bf(p[tt * 4 + 1]) << 16) |
                              (unsigned)(unsigned short)f2bf(p[tt * 4 + 0]);
                unsigned u1 = ((unsigned)(unsigned short)f2bf(p[tt * 4 + 3]) << 16) |
                              (unsigned)(unsigned short)f2bf(p[tt * 4 + 2]);
                int base = lq * 20 + tt * 8 + lg * 2;
                myP32[base] = u0;
                myP32[base + 1] = u1;
            }
            short8_t pa = *(const short8_t*)(myP + lq * 40 + lg * 8);
#pragma unroll
            for (int dt = 0; dt < 8; dt++)
                o[dt] = __builtin_amdgcn_mfma_f32_16x16x32_bf16(pa, vf[dt], o[dt], 0, 0, 0);
        }
        __builtin_amdgcn_sched_barrier(0);
        __builtin_amdgcn_s_barrier();
    }
#undef STAGE

    // ---- combine: each (tile,comp) is complete in one wave ----
    lsum += __shfl_xor(lsum, 16);
    lsum += __shfl_xor(lsum, 32);
    if (l < 16) MLs[w][l] = lsum;
#pragma unroll
    for (int dt = 0; dt < 8; dt++)
#pragma unroll
        for (int r = 0; r < 4; r++) OC[w][lg * 4 + r][dt * 16 + lq] = o[dt][r];
    __syncthreads();

    const int gr = tid >> 3;    // 0..31: tile a rows 0-15, tile b rows 16-31
    const int otile = gr >> 4;
    const int row = gr & 15;
    const int c0 = (tid & 7) * 16;
    const float inv1 = 1.f / MLs[otile * 2][row];
    const float inv2 = lam / MLs[otile * 2 + 1][row];
    float a[16], ss = 0.f;
#pragma unroll
    for (int j = 0; j < 16; j++) {
        a[j] = OC[otile * 2][row][c0 + j] * inv1 - OC[otile * 2 + 1][row][c0 + j] * inv2;
        ss += a[j] * a[j];
    }
    ss += __shfl_xor(ss, 1);
    ss += __shfl_xor(ss, 2);
    ss += __shfl_xor(ss, 4);
    const float sc = rsqrtf(ss * (1.0f / 128.0f) + RMS_EPS) * ONE_MINUS_LI;
    const int qrow = (otile ? q0b : q0a) + row;
    short8_t r8;
#pragma unroll
    for (int j = 0; j < 8; j++) r8[j] = f2bf(a[j] * sc * subln[c0 + j]);
    *(short8_t*)(Ab + (size_t)qrow * EMB + h * DVH + c0) = r8;
#pragma unroll
    for (int j = 0; j < 8; j++) r8[j] = f2bf(a[8 + j] * sc * subln[c0 + 8 + j]);
    *(short8_t*)(Ab + (size_t)qrow * EMB + h * DVH + c0 + 8) = r8;
}

extern "C" void kernel_launch(void* const* d_in, const int* in_sizes, int n_in,
                              void* d_out, int out_size, void* d_ws, size_t ws_size,
                              hipStream_t stream) {
    const float* x = (const float*)d_in[0];
    const float* cosT = (const float*)d_in[1];
    const float* sinT = (const float*)d_in[2];
    const float* wq = (const float*)d_in[3];
    const float* wk = (const float*)d_in[4];
    const float* wv = (const float*)d_in[5];
    const float* wo = (const float*)d_in[6];
    const float* lq1 = (const float*)d_in[7];
    const float* lk1 = (const float*)d_in[8];
    const float* lq2 = (const float*)d_in[9];
    const float* lk2 = (const float*)d_in[10];
    const float* subln = (const float*)d_in[11];
    float* out = (float*)d_out;
    char* ws = (char*)d_ws;
    const size_t MB = 1 << 20;
    short* xb = (short*)(ws);
    short* wqt = (short*)(ws + 4 * MB);
    short* wkt = (short*)(ws + 6 * MB);
    short* wvt = (short*)(ws + 8 * MB);
    short* wot = (short*)(ws + 10 * MB);
    short* Qh = (short*)(ws + 12 * MB);
    short* Kh = (short*)(ws + 16 * MB);
    short* Vb = (short*)(ws + 20 * MB);
    short* Vt = (short*)(ws + 24 * MB);
    short* Ab = (short*)(ws + 28 * MB);
    float* lam = (float*)(ws + 32 * MB);

    k_convert_x<<<2048, 256, 0, stream>>>(x, xb);
    k_transpose_w<<<dim3(16, 16, 4), 256, 0, stream>>>(wq, wk, wv, wo, wqt, wkt, wvt, wot);
    k_lambda<<<1, 64, 0, stream>>>(lq1, lk1, lq2, lk2, lam);
    k_gemm<4, 4, 0><<<dim3(24, 16), 256, 0, stream>>>(xb, wqt, wkt, wvt, Qh, Kh, Vb, nullptr);
    k_rope<<<4096, 256, 0, stream>>>(Qh, Kh, cosT, sinT);
    k_transpose_v<<<dim3(32, 16), 256, 0, stream>>>(Vb, Vt);
    k_attn<<<dim3(64, 8), 256, 0, stream>>>(Qh, Kh, Vt, lam, subln, Ab);
    k_gemm<2, 4, 1><<<dim3(8, 32), 256, 0, stream>>>(Ab, wot, wot, wot, nullptr, nullptr, nullptr, out);
}